// Round 7
// baseline (639.469 us; speedup 1.0000x reference)
//
#include <hip/hip_runtime.h>

// DeepFM: B=16384, D=1024, L=4.
// Round 7: ROW-RESIDENT fusion. Each block owns 64 rows; h lives in LDS
// (64x1024 bf16 = 128 KiB) across all 5 layers -> zero h HBM traffic, zero
// inter-block sync. Weights are read per-block as MFMA B-fragments directly
// from global (L2/L3-resident 2 MB/layer) -> NO LDS staging for B, NO
// barriers in the K-loop (the m97/8-phase barrier-drain problem vanishes).
// Software pipeline: 2-deep named reg buffers (a0/a1, b0/b1), counted
// waits inserted by the compiler (no barriers to defeat them).
// LDS h swizzle: 16B chunk ^ (row&7), applied on initial global_load_lds
// (inverse on source), on ds_read_b128 (A-frags), and on epilogue b16
// writes -> same involution everywhere (rule #21).
// Numerics identical to the multi-kernel version (same bf16 cvts, same
// fp32 accumulation order).

#define DDIM 1024
#define BROWS 16384

typedef __attribute__((ext_vector_type(8))) short s8v;   // 8 bf16
typedef __attribute__((ext_vector_type(4))) float f4v;   // 4 fp32

__device__ __forceinline__ unsigned short f2bf(float f) {
    unsigned int u = __float_as_uint(f);
    u += 0x7fffu + ((u >> 16) & 1u);   // round-to-nearest-even
    return (unsigned short)(u >> 16);
}
__device__ __forceinline__ float bf2f(unsigned short u) {
    return __uint_as_float(((unsigned int)u) << 16);
}
__device__ __forceinline__ void gld16(const void* g, void* l) {
    __builtin_amdgcn_global_load_lds(
        (const __attribute__((address_space(1))) unsigned int*)g,
        (__attribute__((address_space(3))) unsigned int*)l, 16, 0, 0);
}

// -------- fused prep: blocks [0,16384) x rows; [16384, 17664) weights ----
__global__ __launch_bounds__(256) void prep_cvt_kernel(
    const float* __restrict__ x,  const float* __restrict__ Ws,
    const float* __restrict__ Wo, unsigned short* __restrict__ xb,
    unsigned short* __restrict__ wb, float* __restrict__ rowsum)
{
    const int t = threadIdx.x;
    if (blockIdx.x < BROWS) {
        const int row = blockIdx.x;
        const float4 v = *(const float4*)(x + (size_t)row * DDIM + t * 4);
        ushort4 o;
        o.x = f2bf(v.x); o.y = f2bf(v.y); o.z = f2bf(v.z); o.w = f2bf(v.w);
        *(ushort4*)(xb + (size_t)row * DDIM + t * 4) = o;
        float s = v.x + v.y + v.z + v.w;
        #pragma unroll
        for (int off = 32; off > 0; off >>= 1) s += __shfl_down(s, off, 64);
        __shared__ float red[4];
        const int wave = t >> 6, lane = t & 63;
        if (lane == 0) red[wave] = s;
        __syncthreads();
        if (t == 0) rowsum[row] = red[0] + red[1] + red[2] + red[3];
    } else {
        const int base = (blockIdx.x - BROWS) * 1024;
        #pragma unroll
        for (int j = 0; j < 4; ++j) {
            const int idx = base + j * 256 + t;
            const float4 v = (idx < 4 * 262144) ? ((const float4*)Ws)[idx]
                                                : ((const float4*)Wo)[idx - 4 * 262144];
            ushort4 o;
            o.x = f2bf(v.x); o.y = f2bf(v.y); o.z = f2bf(v.z); o.w = f2bf(v.w);
            ((ushort4*)wb)[idx] = o;
        }
    }
}

#define MF(a, b, c) __builtin_amdgcn_mfma_f32_16x16x32_bf16(a, b, c, 0, 0, 0)

// B fragments: 8 cols-frags x 16B/lane from global W (col-major-K rows).
// lane l15 -> col, quad -> k-chunk; consecutive quads contiguous 64B.
#define LOADB(B, kk) { _Pragma("unroll") for (int ni = 0; ni < 8; ++ni)   \
    B[ni] = *(const s8v*)(wB + (size_t)ni * 16384 + (kk) * 32); }

// A fragments from swizzled h-LDS: row = mi*16 + l15, chunk = kk*4+quad.
#define LOADA(A, kk) { _Pragma("unroll") for (int mi = 0; mi < 4; ++mi)   \
    A[mi] = *(const s8v*)((const char*)hL + (mi * 16 + l15) * 2048         \
              + (((((kk) * 4 + quad)) ^ (l15 & 7)) << 4)); }

#define MSTEP(A, B) { __builtin_amdgcn_s_setprio(1);                       \
    _Pragma("unroll") for (int ni = 0; ni < 8; ++ni)                       \
      _Pragma("unroll") for (int mi = 0; mi < 4; ++mi)                     \
        acc[mi][ni] = MF(A[mi], B[ni], acc[mi][ni]);                       \
    __builtin_amdgcn_s_setprio(0); }

__global__ __launch_bounds__(512, 2) void deepfm_rowres(
    const unsigned short* __restrict__ xb, const unsigned short* __restrict__ wb,
    const float* __restrict__ bs, const float* __restrict__ bo,
    const float* __restrict__ rsm, float* __restrict__ out)
{
    __shared__ unsigned short hL[64 * 1024];   // 128 KiB, 16B-chunk swizzled

    const int t = threadIdx.x;        // 0..511
    const int lane = t & 63;
    const int wid  = t >> 6;          // 0..7 -> col slice
    const int l15  = lane & 15;
    const int quad = lane >> 4;
    const int row0 = blockIdx.x * 64;
    const int colS = wid * 128;

    // ---- load xb rows [row0,+64) into hL, swizzled via inverse source ----
    #pragma unroll
    for (int i = 0; i < 16; ++i) {
        const int d = t + i * 512;            // chunk index 0..8191
        const int r = d >> 7, ch = d & 127;
        gld16(xb + (size_t)(row0 + r) * DDIM + (size_t)((ch ^ (r & 7)) * 8),
              (char*)hL + (size_t)d * 16);
    }
    asm volatile("s_waitcnt vmcnt(0)" ::: "memory");
    __syncthreads();

    f4v acc[4][8];
    s8v a0[4], a1[4], b0[8], b1[8];

    #pragma unroll 1
    for (int l = 0; l < 5; ++l) {
        const unsigned short* const wB =
            wb + (size_t)l * DDIM * DDIM + (size_t)(colS + l15) * DDIM + quad * 8;
        const float* const bias = (l == 4) ? bo : (bs + (size_t)l * DDIM);

        #pragma unroll
        for (int mi = 0; mi < 4; ++mi)
            #pragma unroll
            for (int ni = 0; ni < 8; ++ni)
                acc[mi][ni] = (f4v){0.f, 0.f, 0.f, 0.f};

        // ---- K-loop: no barriers; 2-deep software pipeline ---------------
        LOADB(b0, 0); LOADA(a0, 0);
        #pragma unroll 1
        for (int kk = 0; kk < 32; kk += 2) {
            LOADB(b1, kk + 1); LOADA(a1, kk + 1);
            MSTEP(a0, b0);
            if (kk + 2 < 32) { LOADB(b0, kk + 2); LOADA(a0, kk + 2); }
            MSTEP(a1, b1);
        }

        // ---- epilogue. C/D layout: col = l15, row = quad*4 + r -----------
        if (l == 4) {
            // out fp32 = z + bo, direct stores (no LDS dependency)
            #pragma unroll
            for (int ni = 0; ni < 8; ++ni) {
                const int col = colS + ni * 16 + l15;
                const float bv = bias[col];
                #pragma unroll
                for (int mi = 0; mi < 4; ++mi)
                    #pragma unroll
                    for (int r = 0; r < 4; ++r) {
                        const int row = mi * 16 + quad * 4 + r;
                        out[(size_t)(row0 + row) * DDIM + col] = acc[mi][ni][r] + bv;
                    }
            }
        } else {
            __syncthreads();    // all waves done READING hL
            #pragma unroll
            for (int ni = 0; ni < 8; ++ni) {
                const int col = colS + ni * 16 + l15;
                const float bv = bias[col];
                #pragma unroll
                for (int mi = 0; mi < 4; ++mi)
                    #pragma unroll
                    for (int r = 0; r < 4; ++r) {
                        const int row = mi * 16 + quad * 4 + r;
                        float v = acc[mi][ni][r] + bv;
                        v = v > 0.f ? v : 0.f;
                        if (l == 3) {
                            const float rv = rsm[row0 + row];
                            float itv = bf2f(xb[(size_t)(row0 + row) * DDIM + col]) * rv;
                            itv = itv > 0.f ? itv : 0.f;
                            v = 0.5f * (v + itv);
                        }
                        *(unsigned short*)((char*)hL + row * 2048
                            + (((col >> 3) ^ (row & 7)) << 4) + (col & 7) * 2) = f2bf(v);
                    }
            }
            __syncthreads();    // h_{l+1} visible before next K-loop
        }
    }
}

extern "C" void kernel_launch(void* const* d_in, const int* in_sizes, int n_in,
                              void* d_out, int out_size, void* d_ws, size_t ws_size,
                              hipStream_t stream) {
    const float* x  = (const float*)d_in[0];
    const float* Ws = (const float*)d_in[1];
    const float* bs = (const float*)d_in[2];
    const float* Wo = (const float*)d_in[3];
    const float* bo = (const float*)d_in[4];
    float* out = (float*)d_out;

    char* ws = (char*)d_ws;
    unsigned short* xb  = (unsigned short*)(ws);                 // 32 MB bf16 x
    unsigned short* wb  = (unsigned short*)(ws + 33554432);      // 10 MB weights bf16
    float*          rsm = (float*)(ws + 44040192);               // 64 KB rowsum

    prep_cvt_kernel<<<BROWS + 1280, 256, 0, stream>>>(x, Ws, Wo, xb, wb, rsm);
    deepfm_rowres<<<dim3(256), dim3(512), 0, stream>>>(xb, wb, bs, bo, rsm, out);
}

// Round 8
// 332.608 us; speedup vs baseline: 1.9226x; 1.9226x over previous
//
#include <hip/hip_runtime.h>

// DeepFM: B=16384, D=1024, L=4.
// Round 8: multi-kernel (proven 317us) with layer-PAIR merging to cut graph
// node transitions (6 -> 4 nodes, ~12us each). Pairs {0,1} and {2,3} run in
// one kernel with the XCD-local barrier proven in rounds 5/6:
//   block T = xcd*32 + slot owns tile; rows [T>>2]*256 stay on one XCD for
//   both layers -> h edge is same-L2; barrier = device atomicAdd + relaxed
//   agent spin, no cache maintenance. NO SC0 needed: within each paired
//   kernel every buffer is read-touched once (l0:xb,l1:h0 / l2:h1,l3:h0),
//   so no CU can hit a stale L1 line; kernel boundaries invalidate L1.
// GEMM body = round-3's verified 8-phase 256x256 schedule (44us/layer).
// prep zeroes the barrier counters (no memset node).

#define DDIM 1024
#define BROWS 16384
#define NIT 8   // K / 128

typedef __attribute__((ext_vector_type(8))) short s8v;   // 8 bf16
typedef __attribute__((ext_vector_type(4))) float f4v;   // 4 fp32

__device__ __forceinline__ unsigned short f2bf(float f) {
    unsigned int u = __float_as_uint(f);
    u += 0x7fffu + ((u >> 16) & 1u);   // round-to-nearest-even
    return (unsigned short)(u >> 16);
}
__device__ __forceinline__ float bf2f(unsigned short u) {
    return __uint_as_float(((unsigned int)u) << 16);
}
__device__ __forceinline__ void gld16(const void* g, void* l) {
    __builtin_amdgcn_global_load_lds(
        (const __attribute__((address_space(1))) unsigned int*)g,
        (__attribute__((address_space(3))) unsigned int*)l, 16, 0, 0);
}

// -------- fused prep: x->bf16+rowsum, W->bf16, zero barrier counters -----
__global__ __launch_bounds__(256) void prep_cvt_kernel(
    const float* __restrict__ x,  const float* __restrict__ Ws,
    const float* __restrict__ Wo, unsigned short* __restrict__ xb,
    unsigned short* __restrict__ wb, float* __restrict__ rowsum,
    int* __restrict__ cnt)
{
    const int t = threadIdx.x;
    if (blockIdx.x < BROWS) {
        const int row = blockIdx.x;
        const float4 v = *(const float4*)(x + (size_t)row * DDIM + t * 4);
        ushort4 o;
        o.x = f2bf(v.x); o.y = f2bf(v.y); o.z = f2bf(v.z); o.w = f2bf(v.w);
        *(ushort4*)(xb + (size_t)row * DDIM + t * 4) = o;
        float s = v.x + v.y + v.z + v.w;
        #pragma unroll
        for (int off = 32; off > 0; off >>= 1) s += __shfl_down(s, off, 64);
        __shared__ float red[4];
        const int wave = t >> 6, lane = t & 63;
        if (lane == 0) red[wave] = s;
        __syncthreads();
        if (t == 0) rowsum[row] = red[0] + red[1] + red[2] + red[3];
    } else {
        if (blockIdx.x == BROWS && t < 128) cnt[t] = 0;   // slots + barriers
        const int base = (blockIdx.x - BROWS) * 1024;
        #pragma unroll
        for (int j = 0; j < 4; ++j) {
            const int idx = base + j * 256 + t;
            const float4 v = (idx < 4 * 262144) ? ((const float4*)Ws)[idx]
                                                : ((const float4*)Wo)[idx - 4 * 262144];
            ushort4 o;
            o.x = f2bf(v.x); o.y = f2bf(v.y); o.z = f2bf(v.z); o.w = f2bf(v.w);
            ((ushort4*)wb)[idx] = o;
        }
    }
}

#define MF(a, b, c) __builtin_amdgcn_mfma_f32_16x16x32_bf16(a, b, c, 0, 0, 0)
#define BAR()   __builtin_amdgcn_s_barrier()
#define VMC(n)  asm volatile("s_waitcnt vmcnt(" #n ")" ::: "memory")

// byte offset within one 128x64-bf16 half-tile, with 16B-chunk XOR swizzle
#define SWOFF(lr, cc) ((lr) * 128 + ((((cc) ^ ((lr) & 7))) << 4))

#define SH(src, dst) {                                              \
    gld16((src) + soff,                   (char*)(dst) + t * 16);   \
    gld16((src) + soff + (size_t)64 * K,  (char*)(dst) + t * 16 + 8192); }

#define READ_A(P, m0) {                                                               \
    af[0][0] = *(const s8v*)((const char*)(P) + SWOFF((m0) * 16 + mrow,      quad));      \
    af[0][1] = *(const s8v*)((const char*)(P) + SWOFF((m0) * 16 + mrow,      4 + quad));  \
    af[1][0] = *(const s8v*)((const char*)(P) + SWOFF((m0) * 16 + 16 + mrow, quad));      \
    af[1][1] = *(const s8v*)((const char*)(P) + SWOFF((m0) * 16 + 16 + mrow, 4 + quad)); }

#define READ_B(P) {                                                                   \
    bfr[0][0] = *(const s8v*)((const char*)(P) + SWOFF(bl + mrow,      quad));            \
    bfr[0][1] = *(const s8v*)((const char*)(P) + SWOFF(bl + mrow,      4 + quad));        \
    bfr[1][0] = *(const s8v*)((const char*)(P) + SWOFF(bl + 16 + mrow, quad));            \
    bfr[1][1] = *(const s8v*)((const char*)(P) + SWOFF(bl + 16 + mrow, 4 + quad));        \
    bfr[2][0] = *(const s8v*)((const char*)(P) + SWOFF(bl + 32 + mrow, quad));            \
    bfr[2][1] = *(const s8v*)((const char*)(P) + SWOFF(bl + 32 + mrow, 4 + quad));        \
    bfr[3][0] = *(const s8v*)((const char*)(P) + SWOFF(bl + 48 + mrow, quad));            \
    bfr[3][1] = *(const s8v*)((const char*)(P) + SWOFF(bl + 48 + mrow, 4 + quad)); }

#define MMA8(m0, s) {                                              \
    acc[m0][0]       = MF(af[0][s], bfr[0][s], acc[m0][0]);        \
    acc[m0][1]       = MF(af[0][s], bfr[1][s], acc[m0][1]);        \
    acc[m0][2]       = MF(af[0][s], bfr[2][s], acc[m0][2]);        \
    acc[m0][3]       = MF(af[0][s], bfr[3][s], acc[m0][3]);        \
    acc[(m0) + 1][0] = MF(af[1][s], bfr[0][s], acc[(m0) + 1][0]);  \
    acc[(m0) + 1][1] = MF(af[1][s], bfr[1][s], acc[(m0) + 1][1]);  \
    acc[(m0) + 1][2] = MF(af[1][s], bfr[2][s], acc[(m0) + 1][2]);  \
    acc[(m0) + 1][3] = MF(af[1][s], bfr[3][s], acc[(m0) + 1][3]); }

#define MMA16(m0) { __builtin_amdgcn_s_setprio(1); MMA8(m0, 0) MMA8(m0, 1) \
                    __builtin_amdgcn_s_setprio(0); }

// per-XCD barrier: 32 blocks. Device-scope atomicAdd; relaxed agent spin
// (no cache maintenance ops). Stores drained by __syncthreads' vmcnt(0).
__device__ __forceinline__ void xcd_bar(int* bar, int xcd, int ph) {
    __syncthreads();
    if (threadIdx.x == 0) {
        int* c = bar + xcd * 4 + ph;
        atomicAdd(c, 1);
        int guard = 0;
        while (__hip_atomic_load(c, __ATOMIC_RELAXED, __HIP_MEMORY_SCOPE_AGENT) < 32
               && ++guard < (1 << 22))
            __builtin_amdgcn_s_sleep(2);
    }
    __syncthreads();
}

// Runs layers [L0, L0+NL). NL==2: XCD-local tile mapping + 1 barrier.
template <int L0, int NL>
__global__ __launch_bounds__(512, 2) void gemm_chain(
    const float* __restrict__ bs, const float* __restrict__ bo,
    float* __restrict__ out,
    const unsigned short* __restrict__ xb, unsigned short* __restrict__ h0,
    unsigned short* __restrict__ h1, const unsigned short* __restrict__ wb,
    const float* __restrict__ rsm, int* __restrict__ cnt)
{
    constexpr int K = DDIM, N = DDIM;
    __shared__ unsigned short smem[2][2][2][128 * 64];   // 128 KiB

    const int t = threadIdx.x;            // 0..511
    const int lane = t & 63;
    const int wid  = t >> 6;              // 0..7
    const int wr   = wid >> 2;
    const int wc   = wid & 3;
    const int mrow = lane & 15;
    const int quad = lane >> 4;

    int T;
    if (NL > 1) {
        __shared__ int s_T;
        if (t == 0) {
            unsigned xcc;
            asm volatile("s_getreg_b32 %0, hwreg(HW_REG_XCC_ID)" : "=s"(xcc));
            const int xcd_ = (int)(xcc & 7);
            const int slot = atomicAdd(&cnt[xcd_], 1);
            s_T = xcd_ * 32 + slot;
        }
        __syncthreads();
        T = s_T;
    } else {
        T = blockIdx.x;
    }
    const int xcd = T >> 5;
    const int rowBase = (T >> 2) * 256;
    const int colBase = (T & 3) * 256;
    int* const bar = cnt + 8;

    // staging: thread t covers row t>>3 (+64 for 2nd load), 16B chunk t&7.
    const int srow = t >> 3;
    const size_t soff = (size_t)srow * K + (size_t)(((t & 7) ^ (srow & 7)) * 8);

    unsigned short* const a00 = &smem[0][0][0][0];
    unsigned short* const a01 = &smem[0][0][1][0];
    unsigned short* const a10 = &smem[0][1][0][0];
    unsigned short* const a11 = &smem[0][1][1][0];
    unsigned short* const b00 = &smem[1][0][0][0];
    unsigned short* const b01 = &smem[1][0][1][0];
    unsigned short* const b10 = &smem[1][1][0][0];
    unsigned short* const b11 = &smem[1][1][1][0];

    const unsigned short* const aR0 = wr ? a01 : a00;
    const unsigned short* const aR1 = wr ? a11 : a10;
    const unsigned short* const bR0 = (wc >> 1) ? b01 : b00;
    const unsigned short* const bR1 = (wc >> 1) ? b11 : b10;
    const int bl = (wc & 1) * 64;

    #pragma unroll
    for (int i = 0; i < NL; ++i) {
        const int l = L0 + i;
        const unsigned short* Acur = (l == 0) ? xb : ((l & 1) ? h0 : h1);
        const unsigned short* Bwc  = wb + (size_t)l * DDIM * DDIM;
        const float* bias = (l == 4) ? bo : (bs + (size_t)l * DDIM);
        unsigned short* outb = (l & 1) ? h1 : h0;       // used for l < 4

        const unsigned short* const Ab0 = Acur + (size_t)rowBase * K;
        const unsigned short* const Ab1 = Ab0 + (size_t)128 * K;
        const unsigned short* const Bb0 = Bwc + (size_t)colBase * K;
        const unsigned short* const Bb1 = Bb0 + (size_t)128 * K;

        f4v acc[8][4] = {};
        s8v af[2][2], bfr[4][2];

        // ---- prologue: buf0 A+B, buf1 B; wait buf0, let buf1-B fly -------
        SH(Ab0,      a00); SH(Ab1,      a01);
        SH(Bb0,      b00); SH(Bb1,      b01);
        SH(Bb0 + 64, b10); SH(Bb1 + 64, b11);
        VMC(4);
        BAR();
        READ_B(bR0); READ_A(aR0, 0);          // ph1 frags

        #pragma unroll 1
        for (int it = 0; it < NIT; ++it) {
            const int ka = it * 128, kb = ka + 64;
            const bool more = it < NIT - 1;

            // ======== tile a = 2it (buf0), phases 1-4 ========
            SH(Ab0 + kb, a10);
            BAR(); MMA16(0); BAR();
            READ_A(aR0, 2);
            SH(Ab1 + kb, a11);
            BAR(); MMA16(2); BAR();
            READ_A(aR0, 4);
            if (more) SH(Bb0 + ka + 128, b00);
            BAR(); MMA16(4); BAR();
            READ_A(aR0, 6);
            if (more) SH(Bb1 + ka + 128, b01);
            if (more) { VMC(4); } else { VMC(0); }
            BAR();
            MMA16(6);
            READ_B(bR1); READ_A(aR1, 0);      // hoisted ph5 frags
            BAR();

            // ======== tile b = 2it+1 (buf1), phases 5-8 ========
            if (more) SH(Ab0 + ka + 128, a00);
            BAR(); MMA16(0); BAR();
            READ_A(aR1, 2);
            if (more) SH(Ab1 + ka + 128, a01);
            BAR(); MMA16(2); BAR();
            READ_A(aR1, 4);
            if (more) SH(Bb0 + kb + 128, b10);
            BAR(); MMA16(4); BAR();
            READ_A(aR1, 6);
            if (more) SH(Bb1 + kb + 128, b11);
            if (more) { VMC(4); }
            BAR();
            MMA16(6);
            if (more) { READ_B(bR0); READ_A(aR0, 0); }   // next-iter ph1
            BAR();
        }

        // ---- epilogue. C/D layout: col = lane&15, row = quad*4 + reg -----
        if (l == 4) {
            float* sCf = (float*)smem;                 // 128x256 fp32
            #pragma unroll 1
            for (int half = 0; half < 2; ++half) {
                __syncthreads();
                if (wr == half) {
                    #pragma unroll
                    for (int ni = 0; ni < 4; ++ni) {
                        const int n = wc * 64 + ni * 16 + mrow;
                        const float bv = bias[colBase + n];
                        #pragma unroll
                        for (int mi = 0; mi < 8; ++mi)
                            #pragma unroll
                            for (int r = 0; r < 4; ++r)
                                sCf[(mi * 16 + quad * 4 + r) * 256 + n] = acc[mi][ni][r] + bv;
                    }
                }
                __syncthreads();
                #pragma unroll
                for (int p = 0; p < 16; ++p) {
                    const int idx = t + p * 512;       // float4 chunk 0..8191
                    const int row = idx >> 6, ch = idx & 63;
                    const float4 v = ((const float4*)sCf)[idx];
                    *(float4*)(out + (size_t)(rowBase + half * 128 + row) * N + colBase + ch * 4) = v;
                }
            }
        } else {
            __syncthreads();
            unsigned short* sC = (unsigned short*)smem;  // 256x256 bf16
            #pragma unroll
            for (int ni = 0; ni < 4; ++ni) {
                const int n = wc * 64 + ni * 16 + mrow;
                const float bv = bias[colBase + n];
                #pragma unroll
                for (int mi = 0; mi < 8; ++mi)
                    #pragma unroll
                    for (int r = 0; r < 4; ++r) {
                        const int row = wr * 128 + mi * 16 + quad * 4 + r;
                        float v = acc[mi][ni][r] + bv;
                        v = v > 0.f ? v : 0.f;
                        sC[row * 256 + n] = f2bf(v);
                    }
            }
            __syncthreads();
            #pragma unroll
            for (int p = 0; p < 16; ++p) {
                const int idx = t + p * 512;             // ushort8 chunk
                const int row = idx >> 5, ch = idx & 31;
                s8v c = *(const s8v*)&sC[row * 256 + ch * 8];
                if (l == 3) {
                    const float rsv = rsm[rowBase + row];
                    const s8v xv = *(const s8v*)&xb[(size_t)(rowBase + row) * DDIM + colBase + ch * 8];
                    #pragma unroll
                    for (int j = 0; j < 8; ++j) {
                        float itv = bf2f((unsigned short)xv[j]) * rsv;
                        itv = itv > 0.f ? itv : 0.f;
                        c[j] = (short)f2bf(0.5f * (bf2f((unsigned short)c[j]) + itv));
                    }
                }
                *(s8v*)&outb[(size_t)(rowBase + row) * DDIM + colBase + ch * 8] = c;
            }
        }

        if (NL > 1 && i < NL - 1) xcd_bar(bar, xcd, i);
    }
}

extern "C" void kernel_launch(void* const* d_in, const int* in_sizes, int n_in,
                              void* d_out, int out_size, void* d_ws, size_t ws_size,
                              hipStream_t stream) {
    const float* x  = (const float*)d_in[0];
    const float* Ws = (const float*)d_in[1];
    const float* bs = (const float*)d_in[2];
    const float* Wo = (const float*)d_in[3];
    const float* bo = (const float*)d_in[4];
    float* out = (float*)d_out;

    char* ws = (char*)d_ws;
    unsigned short* xb  = (unsigned short*)(ws);                 // 32 MB bf16 x
    unsigned short* h0  = (unsigned short*)(ws + 33554432);      // 32 MB
    unsigned short* h1  = (unsigned short*)(ws + 67108864);      // 32 MB
    unsigned short* wb  = (unsigned short*)(ws + 100663296);     // 10 MB weights bf16
    float*          rsm = (float*)(ws + 111149056);              // 64 KB rowsum

    // 128 ints: [0..63] mega01 (8 slots + barriers), [64..127] mega23.
    int* cnt = (ws_size >= 111214592 + 512)
                   ? (int*)(ws + 111214592)
                   : (int*)((char*)d_out + 67108864 - 512);

    prep_cvt_kernel<<<BROWS + 1280, 256, 0, stream>>>(x, Ws, Wo, xb, wb, rsm, cnt);
    gemm_chain<0, 2><<<256, 512, 0, stream>>>(bs, bo, out, xb, h0, h1, wb, rsm, cnt);
    gemm_chain<2, 2><<<256, 512, 0, stream>>>(bs, bo, out, xb, h0, h1, wb, rsm, cnt + 64);
    gemm_chain<4, 1><<<256, 512, 0, stream>>>(bs, bo, out, xb, h0, h1, wb, rsm, cnt);
}

// Round 9
// 321.563 us; speedup vs baseline: 1.9886x; 1.0343x over previous
//
#include <hip/hip_runtime.h>

// DeepFM: B=16384, D=1024, L=4.
// Round 9: back to the proven 6-dispatch structure (R3, wall 317.7; R8
// showed node-merging doesn't help wall). In-kernel change: SWAPPED-OPERAND
// MFMA (MF(bfr, af)) so the D-fragment is C^T: lane holds 4 consecutive
// h-COLUMNS of one h-row -> epilogue is a direct aligned 8B bf16 (16B fp32
// for layer 4) global store per fragment. Eliminates the entire epilogue
// LDS round-trip: 128 scalar ds_write_b16 (8-way bank conflicts, the 524K
// SQ_LDS_BANK_CONFLICT), 2 syncthreads, 16 ds_read_b128 per layer.
// h stays row-major; staging/K-loop (8-phase counted-vmcnt) unchanged.

#define DDIM 1024
#define BROWS 16384
#define NIT 8   // K / 128

typedef __attribute__((ext_vector_type(8))) short s8v;   // 8 bf16
typedef __attribute__((ext_vector_type(4))) float f4v;   // 4 fp32

__device__ __forceinline__ unsigned short f2bf(float f) {
    unsigned int u = __float_as_uint(f);
    u += 0x7fffu + ((u >> 16) & 1u);   // round-to-nearest-even
    return (unsigned short)(u >> 16);
}
__device__ __forceinline__ float bf2f(unsigned short u) {
    return __uint_as_float(((unsigned int)u) << 16);
}
__device__ __forceinline__ void gld16(const void* g, void* l) {
    __builtin_amdgcn_global_load_lds(
        (const __attribute__((address_space(1))) unsigned int*)g,
        (__attribute__((address_space(3))) unsigned int*)l, 16, 0, 0);
}

// -------- fused prep: blocks [0,16384) x rows; [16384, 17664) weights ----
__global__ __launch_bounds__(256) void prep_cvt_kernel(
    const float* __restrict__ x,  const float* __restrict__ Ws,
    const float* __restrict__ Wo, unsigned short* __restrict__ xb,
    unsigned short* __restrict__ wb, float* __restrict__ rowsum)
{
    const int t = threadIdx.x;
    if (blockIdx.x < BROWS) {
        const int row = blockIdx.x;
        const float4 v = *(const float4*)(x + (size_t)row * DDIM + t * 4);
        ushort4 o;
        o.x = f2bf(v.x); o.y = f2bf(v.y); o.z = f2bf(v.z); o.w = f2bf(v.w);
        *(ushort4*)(xb + (size_t)row * DDIM + t * 4) = o;
        float s = v.x + v.y + v.z + v.w;
        #pragma unroll
        for (int off = 32; off > 0; off >>= 1) s += __shfl_down(s, off, 64);
        __shared__ float red[4];
        const int wave = t >> 6, lane = t & 63;
        if (lane == 0) red[wave] = s;
        __syncthreads();
        if (t == 0) rowsum[row] = red[0] + red[1] + red[2] + red[3];
    } else {
        const int base = (blockIdx.x - BROWS) * 1024;
        #pragma unroll
        for (int j = 0; j < 4; ++j) {
            const int idx = base + j * 256 + t;
            const float4 v = (idx < 4 * 262144) ? ((const float4*)Ws)[idx]
                                                : ((const float4*)Wo)[idx - 4 * 262144];
            ushort4 o;
            o.x = f2bf(v.x); o.y = f2bf(v.y); o.z = f2bf(v.z); o.w = f2bf(v.w);
            ((ushort4*)wb)[idx] = o;
        }
    }
}

// ---------------- GEMM: C = A(MxK) @ Bw(NxK)^T + bias --------------------
#define MF(a, b, c) __builtin_amdgcn_mfma_f32_16x16x32_bf16(a, b, c, 0, 0, 0)
#define BAR()   __builtin_amdgcn_s_barrier()
#define VMC(n)  asm volatile("s_waitcnt vmcnt(" #n ")" ::: "memory")

// byte offset within one 128x64-bf16 half-tile, with 16B-chunk XOR swizzle
#define SWOFF(lr, cc) ((lr) * 128 + ((((cc) ^ ((lr) & 7))) << 4))

#define SH(src, dst) {                                              \
    gld16((src) + soff,                   (char*)(dst) + t * 16);   \
    gld16((src) + soff + (size_t)64 * K,  (char*)(dst) + t * 16 + 8192); }

#define READ_A(P, m0) {                                                               \
    af[0][0] = *(const s8v*)((const char*)(P) + SWOFF((m0) * 16 + mrow,      quad));      \
    af[0][1] = *(const s8v*)((const char*)(P) + SWOFF((m0) * 16 + mrow,      4 + quad));  \
    af[1][0] = *(const s8v*)((const char*)(P) + SWOFF((m0) * 16 + 16 + mrow, quad));      \
    af[1][1] = *(const s8v*)((const char*)(P) + SWOFF((m0) * 16 + 16 + mrow, 4 + quad)); }

#define READ_B(P) {                                                                   \
    bfr[0][0] = *(const s8v*)((const char*)(P) + SWOFF(bl + mrow,      quad));            \
    bfr[0][1] = *(const s8v*)((const char*)(P) + SWOFF(bl + mrow,      4 + quad));        \
    bfr[1][0] = *(const s8v*)((const char*)(P) + SWOFF(bl + 16 + mrow, quad));            \
    bfr[1][1] = *(const s8v*)((const char*)(P) + SWOFF(bl + 16 + mrow, 4 + quad));        \
    bfr[2][0] = *(const s8v*)((const char*)(P) + SWOFF(bl + 32 + mrow, quad));            \
    bfr[2][1] = *(const s8v*)((const char*)(P) + SWOFF(bl + 32 + mrow, 4 + quad));        \
    bfr[3][0] = *(const s8v*)((const char*)(P) + SWOFF(bl + 48 + mrow, quad));            \
    bfr[3][1] = *(const s8v*)((const char*)(P) + SWOFF(bl + 48 + mrow, 4 + quad)); }

// SWAPPED operands: D = W-panel * h-panel^T -> lane&15 = h-row offset,
// quad*4+reg = h-col offset. acc[mi][ni] covers rows mi*16+[0,16) x cols
// ni*16+[0,16) of the wave's 128x64 output, transposed per-fragment.
#define MMA8(m0, s) {                                              \
    acc[m0][0]       = MF(bfr[0][s], af[0][s], acc[m0][0]);        \
    acc[m0][1]       = MF(bfr[1][s], af[0][s], acc[m0][1]);        \
    acc[m0][2]       = MF(bfr[2][s], af[0][s], acc[m0][2]);        \
    acc[m0][3]       = MF(bfr[3][s], af[0][s], acc[m0][3]);        \
    acc[(m0) + 1][0] = MF(bfr[0][s], af[1][s], acc[(m0) + 1][0]);  \
    acc[(m0) + 1][1] = MF(bfr[1][s], af[1][s], acc[(m0) + 1][1]);  \
    acc[(m0) + 1][2] = MF(bfr[2][s], af[1][s], acc[(m0) + 1][2]);  \
    acc[(m0) + 1][3] = MF(bfr[3][s], af[1][s], acc[(m0) + 1][3]); }

#define MMA16(m0) { __builtin_amdgcn_s_setprio(1); MMA8(m0, 0) MMA8(m0, 1) \
                    __builtin_amdgcn_s_setprio(0); }

// MODE 0: out bf16 = relu(z)
// MODE 1: out bf16 = 0.5*(relu(z) + relu(xb*rowsum))   (layer 4 fusion)
// MODE 2: out fp32 = z                                  (final layer)
template <int MODE>
__global__ __launch_bounds__(512, 2) void gemm_bt(
    const unsigned short* __restrict__ A,
    const unsigned short* __restrict__ Bw,
    const float* __restrict__ bias,
    void* __restrict__ out,
    const unsigned short* __restrict__ xb,
    const float* __restrict__ rowsum)
{
    constexpr int K = DDIM, N = DDIM;
    // [A=0/B=1][buf][half][128*64] bf16 = 128 KiB (staging only)
    __shared__ unsigned short smem[2][2][2][128 * 64];

    const int t = threadIdx.x;            // 0..511
    const int lane = t & 63;
    const int wid  = t >> 6;              // 0..7
    const int wr   = wid >> 2;            // 0..1  (M half)
    const int wc   = wid & 3;             // 0..3  (N quarter)
    const int mrow = lane & 15;
    const int quad = lane >> 4;
    const int rowBase = blockIdx.x * 256;
    const int colBase = blockIdx.y * 256;

    const unsigned short* const Ab0 = A  + (size_t)rowBase * K;
    const unsigned short* const Ab1 = Ab0 + (size_t)128 * K;
    const unsigned short* const Bb0 = Bw + (size_t)colBase * K;
    const unsigned short* const Bb1 = Bb0 + (size_t)128 * K;

    // staging: thread t covers row t>>3 (+64 for 2nd load), 16B chunk t&7.
    const int srow = t >> 3;
    const size_t soff = (size_t)srow * K + (size_t)(((t & 7) ^ (srow & 7)) * 8);

    unsigned short* const a00 = &smem[0][0][0][0];
    unsigned short* const a01 = &smem[0][0][1][0];
    unsigned short* const a10 = &smem[0][1][0][0];
    unsigned short* const a11 = &smem[0][1][1][0];
    unsigned short* const b00 = &smem[1][0][0][0];
    unsigned short* const b01 = &smem[1][0][1][0];
    unsigned short* const b10 = &smem[1][1][0][0];
    unsigned short* const b11 = &smem[1][1][1][0];

    const unsigned short* const aR0 = wr ? a01 : a00;       // buf0
    const unsigned short* const aR1 = wr ? a11 : a10;       // buf1
    const unsigned short* const bR0 = (wc >> 1) ? b01 : b00;
    const unsigned short* const bR1 = (wc >> 1) ? b11 : b10;
    const int bl = (wc & 1) * 64;

    f4v acc[8][4] = {};
    s8v af[2][2], bfr[4][2];

    // ---- prologue: buf0 A+B, buf1 B; wait buf0, let buf1-B fly -----------
    SH(Ab0,      a00); SH(Ab1,      a01);
    SH(Bb0,      b00); SH(Bb1,      b01);
    SH(Bb0 + 64, b10); SH(Bb1 + 64, b11);
    VMC(4);
    BAR();
    READ_B(bR0); READ_A(aR0, 0);          // ph1 frags

    #pragma unroll 1
    for (int it = 0; it < NIT; ++it) {
        const int ka = it * 128, kb = ka + 64;
        const bool more = it < NIT - 1;

        // ======== tile a = 2it (buf0), phases 1-4 ========
        SH(Ab0 + kb, a10);
        BAR(); MMA16(0); BAR();
        READ_A(aR0, 2);
        SH(Ab1 + kb, a11);
        BAR(); MMA16(2); BAR();
        READ_A(aR0, 4);
        if (more) SH(Bb0 + ka + 128, b00);
        BAR(); MMA16(4); BAR();
        READ_A(aR0, 6);
        if (more) SH(Bb1 + ka + 128, b01);
        if (more) { VMC(4); } else { VMC(0); }
        BAR();
        MMA16(6);
        READ_B(bR1); READ_A(aR1, 0);      // hoisted ph5 frags
        BAR();

        // ======== tile b = 2it+1 (buf1), phases 5-8 ========
        if (more) SH(Ab0 + ka + 128, a00);
        BAR(); MMA16(0); BAR();
        READ_A(aR1, 2);
        if (more) SH(Ab1 + ka + 128, a01);
        BAR(); MMA16(2); BAR();
        READ_A(aR1, 4);
        if (more) SH(Bb0 + kb + 128, b10);
        BAR(); MMA16(4); BAR();
        READ_A(aR1, 6);
        if (more) SH(Bb1 + kb + 128, b11);
        if (more) { VMC(4); }
        BAR();
        MMA16(6);
        if (more) { READ_B(bR0); READ_A(aR0, 0); }   // next-iter ph1
        BAR();
    }

    // ---- epilogue: direct stores, no LDS, no syncthreads -----------------
    // acc[mi][ni]: h-row = rowBase + wr*128 + mi*16 + mrow,
    //              h-col = colBase + wc*64 + ni*16 + quad*4 + r
    const int colE = colBase + wc * 64 + quad * 4;
    float4 bv[4];
    #pragma unroll
    for (int ni = 0; ni < 4; ++ni) bv[ni] = *(const float4*)&bias[colE + ni * 16];

    if (MODE == 2) {
        float* o = (float*)out;
        #pragma unroll
        for (int mi = 0; mi < 8; ++mi) {
            const int row = rowBase + wr * 128 + mi * 16 + mrow;
            #pragma unroll
            for (int ni = 0; ni < 4; ++ni) {
                float4 ov;
                ov.x = acc[mi][ni][0] + bv[ni].x;
                ov.y = acc[mi][ni][1] + bv[ni].y;
                ov.z = acc[mi][ni][2] + bv[ni].z;
                ov.w = acc[mi][ni][3] + bv[ni].w;
                *(float4*)(o + (size_t)row * N + colE + ni * 16) = ov;
            }
        }
    } else {
        unsigned short* o16 = (unsigned short*)out;
        #pragma unroll
        for (int mi = 0; mi < 8; ++mi) {
            const int row = rowBase + wr * 128 + mi * 16 + mrow;
            float rsv;
            if (MODE == 1) rsv = rowsum[row];
            #pragma unroll
            for (int ni = 0; ni < 4; ++ni) {
                float vv[4];
                vv[0] = acc[mi][ni][0] + bv[ni].x;
                vv[1] = acc[mi][ni][1] + bv[ni].y;
                vv[2] = acc[mi][ni][2] + bv[ni].z;
                vv[3] = acc[mi][ni][3] + bv[ni].w;
                #pragma unroll
                for (int r = 0; r < 4; ++r) vv[r] = vv[r] > 0.f ? vv[r] : 0.f;
                if (MODE == 1) {
                    const ushort4 xv = *(const ushort4*)&xb[(size_t)row * DDIM + colE + ni * 16];
                    float it0 = bf2f(xv.x) * rsv, it1 = bf2f(xv.y) * rsv;
                    float it2 = bf2f(xv.z) * rsv, it3 = bf2f(xv.w) * rsv;
                    it0 = it0 > 0.f ? it0 : 0.f;  it1 = it1 > 0.f ? it1 : 0.f;
                    it2 = it2 > 0.f ? it2 : 0.f;  it3 = it3 > 0.f ? it3 : 0.f;
                    vv[0] = 0.5f * (vv[0] + it0); vv[1] = 0.5f * (vv[1] + it1);
                    vv[2] = 0.5f * (vv[2] + it2); vv[3] = 0.5f * (vv[3] + it3);
                }
                ushort4 o;
                o.x = f2bf(vv[0]); o.y = f2bf(vv[1]);
                o.z = f2bf(vv[2]); o.w = f2bf(vv[3]);
                *(ushort4*)(o16 + (size_t)row * DDIM + colE + ni * 16) = o;
            }
        }
    }
}

extern "C" void kernel_launch(void* const* d_in, const int* in_sizes, int n_in,
                              void* d_out, int out_size, void* d_ws, size_t ws_size,
                              hipStream_t stream) {
    const float* x  = (const float*)d_in[0];
    const float* Ws = (const float*)d_in[1];
    const float* bs = (const float*)d_in[2];
    const float* Wo = (const float*)d_in[3];
    const float* bo = (const float*)d_in[4];
    float* out = (float*)d_out;

    char* ws = (char*)d_ws;
    unsigned short* xb  = (unsigned short*)(ws);                 // 32 MB bf16 x
    unsigned short* h0  = (unsigned short*)(ws + 33554432);      // 32 MB
    unsigned short* h1  = (unsigned short*)(ws + 67108864);      // 32 MB
    unsigned short* wb  = (unsigned short*)(ws + 100663296);     // 10 MB weights bf16
    float*          rsm = (float*)(ws + 111149056);              // 64 KB rowsum

    prep_cvt_kernel<<<BROWS + 1280, 256, 0, stream>>>(x, Ws, Wo, xb, wb, rsm);

    const size_t WSZ = (size_t)DDIM * DDIM;
    dim3 g(BROWS / 256, DDIM / 256);
    gemm_bt<0><<<g, 512, 0, stream>>>(xb, wb,           bs,            h0, nullptr, nullptr);
    gemm_bt<0><<<g, 512, 0, stream>>>(h0, wb + 1 * WSZ, bs + 1 * DDIM, h1, nullptr, nullptr);
    gemm_bt<0><<<g, 512, 0, stream>>>(h1, wb + 2 * WSZ, bs + 2 * DDIM, h0, nullptr, nullptr);
    gemm_bt<1><<<g, 512, 0, stream>>>(h0, wb + 3 * WSZ, bs + 3 * DDIM, h1, xb, rsm);
    gemm_bt<2><<<g, 512, 0, stream>>>(h1, wb + 4 * WSZ, bo,            out, nullptr, nullptr);
}

// Round 10
// 315.426 us; speedup vs baseline: 2.0273x; 1.0195x over previous
//
#include <hip/hip_runtime.h>

// DeepFM: B=16384, D=1024, L=4.
// Round 10: BARRIER-LIGHT K-loop. R9 showed the kernel is not HBM/VALU/
// conflict/MFMA-issue bound (1650 cyc/phase vs ~500 of work); the remaining
// candidate is the 16-barrier/iter lockstep. Correctness rule: a buffer may
// be overwritten iff a barrier postdates all reads of it. That needs only
// 4 barriers/iter: 2 VMC checkpoints + 1 after each half's first MMA16
// (B-frags of the half are fully lgkm-consumed by then; the half's later
// phases overwrite those B buffers). A-buffer overwrites are covered by the
// checkpoints. vmcnt invariants unchanged (same issue points, per-wave).
// Epilogue: swapped-operand direct stores (R9; 0 bank conflicts, no LDS).

#define DDIM 1024
#define BROWS 16384
#define NIT 8   // K / 128

typedef __attribute__((ext_vector_type(8))) short s8v;   // 8 bf16
typedef __attribute__((ext_vector_type(4))) float f4v;   // 4 fp32

__device__ __forceinline__ unsigned short f2bf(float f) {
    unsigned int u = __float_as_uint(f);
    u += 0x7fffu + ((u >> 16) & 1u);   // round-to-nearest-even
    return (unsigned short)(u >> 16);
}
__device__ __forceinline__ float bf2f(unsigned short u) {
    return __uint_as_float(((unsigned int)u) << 16);
}
__device__ __forceinline__ void gld16(const void* g, void* l) {
    __builtin_amdgcn_global_load_lds(
        (const __attribute__((address_space(1))) unsigned int*)g,
        (__attribute__((address_space(3))) unsigned int*)l, 16, 0, 0);
}

// -------- fused prep: blocks [0,16384) x rows; [16384, 17664) weights ----
__global__ __launch_bounds__(256) void prep_cvt_kernel(
    const float* __restrict__ x,  const float* __restrict__ Ws,
    const float* __restrict__ Wo, unsigned short* __restrict__ xb,
    unsigned short* __restrict__ wb, float* __restrict__ rowsum)
{
    const int t = threadIdx.x;
    if (blockIdx.x < BROWS) {
        const int row = blockIdx.x;
        const float4 v = *(const float4*)(x + (size_t)row * DDIM + t * 4);
        ushort4 o;
        o.x = f2bf(v.x); o.y = f2bf(v.y); o.z = f2bf(v.z); o.w = f2bf(v.w);
        *(ushort4*)(xb + (size_t)row * DDIM + t * 4) = o;
        float s = v.x + v.y + v.z + v.w;
        #pragma unroll
        for (int off = 32; off > 0; off >>= 1) s += __shfl_down(s, off, 64);
        __shared__ float red[4];
        const int wave = t >> 6, lane = t & 63;
        if (lane == 0) red[wave] = s;
        __syncthreads();
        if (t == 0) rowsum[row] = red[0] + red[1] + red[2] + red[3];
    } else {
        const int base = (blockIdx.x - BROWS) * 1024;
        #pragma unroll
        for (int j = 0; j < 4; ++j) {
            const int idx = base + j * 256 + t;
            const float4 v = (idx < 4 * 262144) ? ((const float4*)Ws)[idx]
                                                : ((const float4*)Wo)[idx - 4 * 262144];
            ushort4 o;
            o.x = f2bf(v.x); o.y = f2bf(v.y); o.z = f2bf(v.z); o.w = f2bf(v.w);
            ((ushort4*)wb)[idx] = o;
        }
    }
}

// ---------------- GEMM: C = A(MxK) @ Bw(NxK)^T + bias --------------------
#define MF(a, b, c) __builtin_amdgcn_mfma_f32_16x16x32_bf16(a, b, c, 0, 0, 0)
#define BAR()   __builtin_amdgcn_s_barrier()
#define VMC(n)  asm volatile("s_waitcnt vmcnt(" #n ")" ::: "memory")

// byte offset within one 128x64-bf16 half-tile, with 16B-chunk XOR swizzle
#define SWOFF(lr, cc) ((lr) * 128 + ((((cc) ^ ((lr) & 7))) << 4))

#define SH(src, dst) {                                              \
    gld16((src) + soff,                   (char*)(dst) + t * 16);   \
    gld16((src) + soff + (size_t)64 * K,  (char*)(dst) + t * 16 + 8192); }

#define READ_A(P, m0) {                                                               \
    af[0][0] = *(const s8v*)((const char*)(P) + SWOFF((m0) * 16 + mrow,      quad));      \
    af[0][1] = *(const s8v*)((const char*)(P) + SWOFF((m0) * 16 + mrow,      4 + quad));  \
    af[1][0] = *(const s8v*)((const char*)(P) + SWOFF((m0) * 16 + 16 + mrow, quad));      \
    af[1][1] = *(const s8v*)((const char*)(P) + SWOFF((m0) * 16 + 16 + mrow, 4 + quad)); }

#define READ_B(P) {                                                                   \
    bfr[0][0] = *(const s8v*)((const char*)(P) + SWOFF(bl + mrow,      quad));            \
    bfr[0][1] = *(const s8v*)((const char*)(P) + SWOFF(bl + mrow,      4 + quad));        \
    bfr[1][0] = *(const s8v*)((const char*)(P) + SWOFF(bl + 16 + mrow, quad));            \
    bfr[1][1] = *(const s8v*)((const char*)(P) + SWOFF(bl + 16 + mrow, 4 + quad));        \
    bfr[2][0] = *(const s8v*)((const char*)(P) + SWOFF(bl + 32 + mrow, quad));            \
    bfr[2][1] = *(const s8v*)((const char*)(P) + SWOFF(bl + 32 + mrow, 4 + quad));        \
    bfr[3][0] = *(const s8v*)((const char*)(P) + SWOFF(bl + 48 + mrow, quad));            \
    bfr[3][1] = *(const s8v*)((const char*)(P) + SWOFF(bl + 48 + mrow, 4 + quad)); }

// SWAPPED operands: D = W-panel * h-panel^T -> lane&15 = h-row offset,
// quad*4+reg = h-col offset (direct row-major global stores in epilogue).
#define MMA8(m0, s) {                                              \
    acc[m0][0]       = MF(bfr[0][s], af[0][s], acc[m0][0]);        \
    acc[m0][1]       = MF(bfr[1][s], af[0][s], acc[m0][1]);        \
    acc[m0][2]       = MF(bfr[2][s], af[0][s], acc[m0][2]);        \
    acc[m0][3]       = MF(bfr[3][s], af[0][s], acc[m0][3]);        \
    acc[(m0) + 1][0] = MF(bfr[0][s], af[1][s], acc[(m0) + 1][0]);  \
    acc[(m0) + 1][1] = MF(bfr[1][s], af[1][s], acc[(m0) + 1][1]);  \
    acc[(m0) + 1][2] = MF(bfr[2][s], af[1][s], acc[(m0) + 1][2]);  \
    acc[(m0) + 1][3] = MF(bfr[3][s], af[1][s], acc[(m0) + 1][3]); }

#define MMA16(m0) { __builtin_amdgcn_s_setprio(1); MMA8(m0, 0) MMA8(m0, 1) \
                    __builtin_amdgcn_s_setprio(0); }

// MODE 0: out bf16 = relu(z)
// MODE 1: out bf16 = 0.5*(relu(z) + relu(xb*rowsum))   (layer 4 fusion)
// MODE 2: out fp32 = z                                  (final layer)
template <int MODE>
__global__ __launch_bounds__(512, 2) void gemm_bt(
    const unsigned short* __restrict__ A,
    const unsigned short* __restrict__ Bw,
    const float* __restrict__ bias,
    void* __restrict__ out,
    const unsigned short* __restrict__ xb,
    const float* __restrict__ rowsum)
{
    constexpr int K = DDIM, N = DDIM;
    // [A=0/B=1][buf][half][128*64] bf16 = 128 KiB (staging only)
    __shared__ unsigned short smem[2][2][2][128 * 64];

    const int t = threadIdx.x;            // 0..511
    const int lane = t & 63;
    const int wid  = t >> 6;              // 0..7
    const int wr   = wid >> 2;            // 0..1  (M half)
    const int wc   = wid & 3;             // 0..3  (N quarter)
    const int mrow = lane & 15;
    const int quad = lane >> 4;
    const int rowBase = blockIdx.x * 256;
    const int colBase = blockIdx.y * 256;

    const unsigned short* const Ab0 = A  + (size_t)rowBase * K;
    const unsigned short* const Ab1 = Ab0 + (size_t)128 * K;
    const unsigned short* const Bb0 = Bw + (size_t)colBase * K;
    const unsigned short* const Bb1 = Bb0 + (size_t)128 * K;

    // staging: thread t covers row t>>3 (+64 for 2nd load), 16B chunk t&7.
    const int srow = t >> 3;
    const size_t soff = (size_t)srow * K + (size_t)(((t & 7) ^ (srow & 7)) * 8);

    unsigned short* const a00 = &smem[0][0][0][0];
    unsigned short* const a01 = &smem[0][0][1][0];
    unsigned short* const a10 = &smem[0][1][0][0];
    unsigned short* const a11 = &smem[0][1][1][0];
    unsigned short* const b00 = &smem[1][0][0][0];
    unsigned short* const b01 = &smem[1][0][1][0];
    unsigned short* const b10 = &smem[1][1][0][0];
    unsigned short* const b11 = &smem[1][1][1][0];

    const unsigned short* const aR0 = wr ? a01 : a00;       // buf0
    const unsigned short* const aR1 = wr ? a11 : a10;       // buf1
    const unsigned short* const bR0 = (wc >> 1) ? b01 : b00;
    const unsigned short* const bR1 = (wc >> 1) ? b11 : b10;
    const int bl = (wc & 1) * 64;

    f4v acc[8][4] = {};
    s8v af[2][2], bfr[4][2];

    // ---- prologue: buf0 A+B, buf1 B; wait buf0, let buf1-B fly -----------
    SH(Ab0,      a00); SH(Ab1,      a01);
    SH(Bb0,      b00); SH(Bb1,      b01);
    SH(Bb0 + 64, b10); SH(Bb1 + 64, b11);
    VMC(4);
    BAR();
    READ_B(bR0); READ_A(aR0, 0);          // buf0 frags

    #pragma unroll 1
    for (int it = 0; it < NIT; ++it) {
        const int ka = it * 128, kb = ka + 64;
        const bool more = it < NIT - 1;

        // ==== half A: consume buf0 (phases 1-4, barrier-light) ====
        SH(Ab0 + kb, a10);
        MMA16(0);
        BAR();   // B-buf0 frags consumed by all waves -> b00/b01 reusable
        READ_A(aR0, 2);
        SH(Ab1 + kb, a11);
        MMA16(2);
        READ_A(aR0, 4);
        if (more) SH(Bb0 + ka + 128, b00);
        MMA16(4);
        READ_A(aR0, 6);
        if (more) SH(Bb1 + ka + 128, b01);
        MMA16(6);
        if (more) { VMC(4); } else { VMC(0); }
        BAR();   // checkpoint: buf1 (A+B) landed for all waves
        READ_B(bR1); READ_A(aR1, 0);

        // ==== half B: consume buf1 (phases 5-8) ====
        if (more) SH(Ab0 + ka + 128, a00);
        MMA16(0);
        BAR();   // B-buf1 frags consumed -> b10/b11 reusable
        READ_A(aR1, 2);
        if (more) SH(Ab1 + ka + 128, a01);
        MMA16(2);
        READ_A(aR1, 4);
        if (more) SH(Bb0 + kb + 128, b10);
        MMA16(4);
        READ_A(aR1, 6);
        if (more) SH(Bb1 + kb + 128, b11);
        MMA16(6);
        if (more) {
            VMC(4);
            BAR();   // checkpoint: next buf0 (A+B) landed
            READ_B(bR0); READ_A(aR0, 0);
        }
    }

    // ---- epilogue: direct stores, no LDS, no syncthreads -----------------
    // acc[mi][ni]: h-row = rowBase + wr*128 + mi*16 + mrow,
    //              h-col = colBase + wc*64 + ni*16 + quad*4 + r
    const int colE = colBase + wc * 64 + quad * 4;
    float4 bv[4];
    #pragma unroll
    for (int ni = 0; ni < 4; ++ni) bv[ni] = *(const float4*)&bias[colE + ni * 16];

    if (MODE == 2) {
        float* o = (float*)out;
        #pragma unroll
        for (int mi = 0; mi < 8; ++mi) {
            const int row = rowBase + wr * 128 + mi * 16 + mrow;
            #pragma unroll
            for (int ni = 0; ni < 4; ++ni) {
                float4 ov;
                ov.x = acc[mi][ni][0] + bv[ni].x;
                ov.y = acc[mi][ni][1] + bv[ni].y;
                ov.z = acc[mi][ni][2] + bv[ni].z;
                ov.w = acc[mi][ni][3] + bv[ni].w;
                *(float4*)(o + (size_t)row * N + colE + ni * 16) = ov;
            }
        }
    } else {
        unsigned short* o16 = (unsigned short*)out;
        #pragma unroll
        for (int mi = 0; mi < 8; ++mi) {
            const int row = rowBase + wr * 128 + mi * 16 + mrow;
            float rsv;
            if (MODE == 1) rsv = rowsum[row];
            #pragma unroll
            for (int ni = 0; ni < 4; ++ni) {
                float vv[4];
                vv[0] = acc[mi][ni][0] + bv[ni].x;
                vv[1] = acc[mi][ni][1] + bv[ni].y;
                vv[2] = acc[mi][ni][2] + bv[ni].z;
                vv[3] = acc[mi][ni][3] + bv[ni].w;
                #pragma unroll
                for (int r = 0; r < 4; ++r) vv[r] = vv[r] > 0.f ? vv[r] : 0.f;
                if (MODE == 1) {
                    const ushort4 xv = *(const ushort4*)&xb[(size_t)row * DDIM + colE + ni * 16];
                    float it0 = bf2f(xv.x) * rsv, it1 = bf2f(xv.y) * rsv;
                    float it2 = bf2f(xv.z) * rsv, it3 = bf2f(xv.w) * rsv;
                    it0 = it0 > 0.f ? it0 : 0.f;  it1 = it1 > 0.f ? it1 : 0.f;
                    it2 = it2 > 0.f ? it2 : 0.f;  it3 = it3 > 0.f ? it3 : 0.f;
                    vv[0] = 0.5f * (vv[0] + it0); vv[1] = 0.5f * (vv[1] + it1);
                    vv[2] = 0.5f * (vv[2] + it2); vv[3] = 0.5f * (vv[3] + it3);
                }
                ushort4 o;
                o.x = f2bf(vv[0]); o.y = f2bf(vv[1]);
                o.z = f2bf(vv[2]); o.w = f2bf(vv[3]);
                *(ushort4*)(o16 + (size_t)row * DDIM + colE + ni * 16) = o;
            }
        }
    }
}

extern "C" void kernel_launch(void* const* d_in, const int* in_sizes, int n_in,
                              void* d_out, int out_size, void* d_ws, size_t ws_size,
                              hipStream_t stream) {
    const float* x  = (const float*)d_in[0];
    const float* Ws = (const float*)d_in[1];
    const float* bs = (const float*)d_in[2];
    const float* Wo = (const float*)d_in[3];
    const float* bo = (const float*)d_in[4];
    float* out = (float*)d_out;

    char* ws = (char*)d_ws;
    unsigned short* xb  = (unsigned short*)(ws);                 // 32 MB bf16 x
    unsigned short* h0  = (unsigned short*)(ws + 33554432);      // 32 MB
    unsigned short* h1  = (unsigned short*)(ws + 67108864);      // 32 MB
    unsigned short* wb  = (unsigned short*)(ws + 100663296);     // 10 MB weights bf16
    float*          rsm = (float*)(ws + 111149056);              // 64 KB rowsum

    prep_cvt_kernel<<<BROWS + 1280, 256, 0, stream>>>(x, Ws, Wo, xb, wb, rsm);

    const size_t WSZ = (size_t)DDIM * DDIM;
    dim3 g(BROWS / 256, DDIM / 256);
    gemm_bt<0><<<g, 512, 0, stream>>>(xb, wb,           bs,            h0, nullptr, nullptr);
    gemm_bt<0><<<g, 512, 0, stream>>>(h0, wb + 1 * WSZ, bs + 1 * DDIM, h1, nullptr, nullptr);
    gemm_bt<0><<<g, 512, 0, stream>>>(h1, wb + 2 * WSZ, bs + 2 * DDIM, h0, nullptr, nullptr);
    gemm_bt<1><<<g, 512, 0, stream>>>(h0, wb + 3 * WSZ, bs + 3 * DDIM, h1, xb, rsm);
    gemm_bt<2><<<g, 512, 0, stream>>>(h1, wb + 4 * WSZ, bo,            out, nullptr, nullptr);
}